// Round 1
// baseline (1819.775 us; speedup 1.0000x reference)
//
#include <hip/hip_runtime.h>
#include <hip/hip_bf16.h>

// ---------------- workspace layout (float offsets) ----------------
// w1t:       0 ..   3456   [tap216][oc16]
// w2t:    3456 ..  67456   [ic*125+tap][oc32]
// w3t:   67456 .. 259456   [ic*125+tap][oc48]
// w4t:  259456 .. 342400   [ic*27+tap][oc64]
// h2a:  342400 .. 5962112  partial conv2 (ic 0..7) -> becomes final h2
// h2b: 5962112 .. 11581824 partial conv2 (ic 8..15)
// h3p: 11581824 .. 12368256  4 partials of conv3
// h3:  12368256 .. 12564864
// feat:12564864 .. 12597632  [64][512]
// M:   12597632 .. 12663168  [64][1024]
// oT:  12663168 .. 12667264  [64][64]
// h1:  12667264 .. 34474368  batch buffer [16n][16oc][44][44][44]

static inline __device__ float leaky(float v) { return v >= 0.f ? v : 0.01f * v; }

// dst[t*OC + oc] = src[oc*TAPS + t]
__global__ void transpose_w(const float* __restrict__ src, float* __restrict__ dst,
                            int OC, int TAPS) {
    int i = blockIdx.x * 256 + threadIdx.x;
    if (i < OC * TAPS) {
        int oc = i % OC;
        int t  = i / OC;
        dst[i] = src[oc * TAPS + t];
    }
}

// conv1: x[64,1,92,92,92] -> h1[16nb,16,44,44,44], k=6, s=2
// thread: 4 z outputs x 16 oc
__global__ __launch_bounds__(256) void conv1_kernel(
    const float* __restrict__ x, const float* __restrict__ w1t,
    const float* __restrict__ b1, float* __restrict__ h1, int n0) {
    __shared__ float wl[216 * 16];
    int tid = threadIdx.x;
    for (int i = tid; i < 216 * 16; i += 256) wl[i] = w1t[i];
    __syncthreads();

    long o = (long)blockIdx.x * 256 + tid;  // 16*11*44*44 = 340736 exactly
    int xo = (int)(o % 44); o /= 44;
    int yo = (int)(o % 44); o /= 44;
    int zq = (int)(o % 11);
    int nb = (int)(o / 11);
    int n  = n0 + nb;

    const float* xin = x + (long)n * 778688;  // 92^3
    float acc[4][16];
#pragma unroll
    for (int j = 0; j < 4; j++)
#pragma unroll
        for (int q = 0; q < 16; q++) acc[j][q] = 0.f;

    int z0 = zq * 4;
    int izb = 2 * z0, iyb = 2 * yo, ixb = 2 * xo;

    for (int kz = 0; kz < 6; kz++) {
        for (int ky = 0; ky < 6; ky++) {
            const float* xr = xin + (long)(izb + kz) * 8464 + (iyb + ky) * 92 + ixb;
            int tbase = (kz * 36 + ky * 6) * 16;
#pragma unroll
            for (int kx = 0; kx < 6; kx++) {
                float v0 = xr[kx];
                float v1 = xr[kx + 2 * 8464];
                float v2 = xr[kx + 4 * 8464];
                float v3 = xr[kx + 6 * 8464];
                const float4* wp4 = (const float4*)&wl[tbase + kx * 16];
#pragma unroll
                for (int q = 0; q < 4; q++) {
                    float4 w = wp4[q];
                    float wv0 = w.x, wv1 = w.y, wv2 = w.z, wv3 = w.w;
                    acc[0][q*4+0] += v0*wv0; acc[0][q*4+1] += v0*wv1; acc[0][q*4+2] += v0*wv2; acc[0][q*4+3] += v0*wv3;
                    acc[1][q*4+0] += v1*wv0; acc[1][q*4+1] += v1*wv1; acc[1][q*4+2] += v1*wv2; acc[1][q*4+3] += v1*wv3;
                    acc[2][q*4+0] += v2*wv0; acc[2][q*4+1] += v2*wv1; acc[2][q*4+2] += v2*wv2; acc[2][q*4+3] += v2*wv3;
                    acc[3][q*4+0] += v3*wv0; acc[3][q*4+1] += v3*wv1; acc[3][q*4+2] += v3*wv2; acc[3][q*4+3] += v3*wv3;
                }
            }
        }
    }

    // h1 layout: [nb][oc16][z44][y44][x44]
#pragma unroll
    for (int oc = 0; oc < 16; oc++) {
        float bb = b1[oc];
#pragma unroll
        for (int j = 0; j < 4; j++) {
            long idx = ((long)(nb * 16 + oc) * 44 + (z0 + j)) * 1936 + yo * 44 + xo;
            h1[idx] = leaky(acc[j][oc] + bb);
        }
    }
}

// conv2: h1[16nb,16,44,44,44] -> partials [n,32,14,14,14], k=5, s=3
// thread: 2 z outputs (z, z+7) x 16 oc x 8 ic (icg = blockIdx.y)
__global__ __launch_bounds__(256) void conv2_kernel(
    const float* __restrict__ h1, const float* __restrict__ w2t,
    float* __restrict__ h2a, float* __restrict__ h2b, int g) {
    __shared__ float wl[125 * 32];
    int tid = threadIdx.x;
    int icg = blockIdx.y;

    long o = (long)blockIdx.x * 256 + tid;
    bool valid = o < 43904;  // 16n * 7zq * 14y * 14x * 2ocg
    int xo = 0, yo = 0, zq = 0, nb = 0, ocg = 0;
    if (valid) {
        xo = (int)(o % 14); o /= 14;
        yo = (int)(o % 14); o /= 14;
        zq = (int)(o % 7);  o /= 7;
        nb = (int)(o % 16);
        ocg = (int)(o / 16);
    }

    float acc[2][16];
#pragma unroll
    for (int j = 0; j < 2; j++)
#pragma unroll
        for (int q = 0; q < 16; q++) acc[j][q] = 0.f;

    const float* xin = h1 + (long)nb * 16 * 85184;

    for (int ic = 0; ic < 8; ic++) {
        int ica = icg * 8 + ic;
        __syncthreads();
        for (int i = tid; i < 4000; i += 256) wl[i] = w2t[(long)ica * 4000 + i];
        __syncthreads();
        if (!valid) continue;
        const float* xc = xin + (long)ica * 85184;
        for (int kz = 0; kz < 5; kz++) {
            int iz = 3 * zq + kz;
            for (int ky = 0; ky < 5; ky++) {
                const float* xr = xc + (iz * 44 + (3 * yo + ky)) * 44 + 3 * xo;
                int tb = ((kz * 5 + ky) * 5) * 32 + ocg * 16;
#pragma unroll
                for (int kx = 0; kx < 5; kx++) {
                    float v0 = xr[kx];
                    float v1 = xr[kx + 21 * 1936];  // z+7 -> iz+21
                    const float4* wp = (const float4*)&wl[tb + kx * 32];
#pragma unroll
                    for (int q = 0; q < 4; q++) {
                        float4 w = wp[q];
                        acc[0][q*4+0] += v0*w.x; acc[0][q*4+1] += v0*w.y; acc[0][q*4+2] += v0*w.z; acc[0][q*4+3] += v0*w.w;
                        acc[1][q*4+0] += v1*w.x; acc[1][q*4+1] += v1*w.y; acc[1][q*4+2] += v1*w.z; acc[1][q*4+3] += v1*w.w;
                    }
                }
            }
        }
    }

    if (valid) {
        float* dst = (icg == 0) ? h2a : h2b;
        int n = g * 16 + nb;
#pragma unroll
        for (int j = 0; j < 2; j++) {
            int z = zq + j * 7;
            long base = ((long)(n * 32 + ocg * 16)) * 2744 + (z * 14 + yo) * 14 + xo;
#pragma unroll
            for (int q = 0; q < 16; q++) dst[base + (long)q * 2744] = acc[j][q];
        }
    }
}

// h2 = leaky(h2a + h2b + b2[oc]) in-place into h2a
__global__ void combine2(float* __restrict__ a, const float* __restrict__ b,
                         const float* __restrict__ b2) {
    long i = (long)blockIdx.x * 256 + threadIdx.x;  // 5619712 exactly = 21952*256
    int oc = (int)((i / 2744) % 32);
    a[i] = leaky(a[i] + b[i] + b2[oc]);
}

// conv3: h2[64,32,14,14,14] -> h3p[icg][64,48,4,4,4], k=5, s=3
// grid 256: block = (n, icg); wave = 12 oc; lane = 64 positions
__global__ __launch_bounds__(256) void conv3_kernel(
    const float* __restrict__ h2, const float* __restrict__ w3t,
    float* __restrict__ h3p) {
    int n   = blockIdx.x % 64;
    int icg = blockIdx.x / 64;
    int lane = threadIdx.x % 64;
    int wv   = threadIdx.x / 64;
    int ocb  = wv * 12;
    int xo = lane % 4, yo = (lane / 4) % 4, zo = lane / 16;

    float acc[12];
#pragma unroll
    for (int q = 0; q < 12; q++) acc[q] = 0.f;

    for (int ic = icg * 8; ic < icg * 8 + 8; ic++) {
        const float* xc = h2 + ((long)n * 32 + ic) * 2744;
        for (int kz = 0; kz < 5; kz++) {
            for (int ky = 0; ky < 5; ky++) {
                const float* xr = xc + ((3 * zo + kz) * 14 + 3 * yo + ky) * 14 + 3 * xo;
                int tb = ic * 125 + (kz * 5 + ky) * 5;
#pragma unroll
                for (int kx = 0; kx < 5; kx++) {
                    float v = xr[kx];
                    const float4* wp = (const float4*)&w3t[(long)(tb + kx) * 48 + ocb];
#pragma unroll
                    for (int q = 0; q < 3; q++) {
                        float4 w = wp[q];
                        acc[q*4+0] += v*w.x; acc[q*4+1] += v*w.y; acc[q*4+2] += v*w.z; acc[q*4+3] += v*w.w;
                    }
                }
            }
        }
    }
    float* outp = h3p + (long)icg * 196608 + ((long)n * 48 + ocb) * 64 + lane;
#pragma unroll
    for (int j = 0; j < 12; j++) outp[(long)j * 64] = acc[j];
}

// h3 = leaky(sum of 4 partials + b3[oc])
__global__ void combine3(float* __restrict__ h3, const float* __restrict__ h3p,
                         const float* __restrict__ b3) {
    long i = (long)blockIdx.x * 256 + threadIdx.x;  // 196608 = 768*256
    int oc = (int)((i / 64) % 48);
    float v = h3p[i] + h3p[i + 196608] + h3p[i + 2 * 196608] + h3p[i + 3 * 196608] + b3[oc];
    h3[i] = leaky(v);
}

// conv4: h3[64,48,4,4,4] -> feat[64,512], k=3, s=1
__global__ void conv4_kernel(const float* __restrict__ h3, const float* __restrict__ w4t,
                             const float* __restrict__ b4, float* __restrict__ feat) {
    int o = blockIdx.x * 256 + threadIdx.x;  // 32768 = 128*256
    int pos = o & 7;
    int oc  = (o >> 3) & 63;
    int n   = o >> 9;
    int px = pos & 1, py = (pos >> 1) & 1, pz = pos >> 2;
    const float* xn = h3 + (long)n * 48 * 64;
    float acc = 0.f;
    for (int ic = 0; ic < 48; ic++) {
        const float* xc = xn + ic * 64;
        int tb = ic * 27;
#pragma unroll
        for (int kz = 0; kz < 3; kz++)
#pragma unroll
            for (int ky = 0; ky < 3; ky++)
#pragma unroll
                for (int kx = 0; kx < 3; kx++) {
                    float v = xc[(pz + kz) * 16 + (py + ky) * 4 + (px + kx)];
                    acc += v * w4t[(long)(tb + (kz * 3 + ky) * 3 + kx) * 64 + oc];
                }
    }
    feat[o] = leaky(acc + b4[oc]);  // o == n*512 + oc*8 + pos
}

// M[64,1024] = feat[64,512] @ T[512,1024]
__global__ void m_kernel(const float* __restrict__ feat, const float* __restrict__ T,
                         float* __restrict__ M) {
    int o = blockIdx.x * 256 + threadIdx.x;  // 65536 = 256*256
    int col = o & 1023;
    int n   = o >> 10;
    const float* fr = feat + n * 512;
    float acc = 0.f;
#pragma unroll 4
    for (int f = 0; f < 512; f++) acc += fr[f] * T[f * 1024 + col];
    M[o] = acc;
}

// out_T[i,k] = sum_j exp( sum_l |M[i,k,l]-M[j,k,l]| )
__global__ void outt_kernel(const float* __restrict__ M, float* __restrict__ oT) {
    int o = blockIdx.x * 256 + threadIdx.x;  // 4096 = 16*256
    int k = o & 63;
    int i = o >> 6;
    float mi[16];
    const float4* Mi = (const float4*)(M + i * 1024 + k * 16);
#pragma unroll
    for (int q = 0; q < 4; q++) {
        float4 a = Mi[q];
        mi[q*4+0] = a.x; mi[q*4+1] = a.y; mi[q*4+2] = a.z; mi[q*4+3] = a.w;
    }
    float s = 0.f;
    for (int j = 0; j < 64; j++) {
        const float4* Mj = (const float4*)(M + j * 1024 + k * 16);
        float d = 0.f;
#pragma unroll
        for (int q = 0; q < 4; q++) {
            float4 a = Mj[q];
            d += fabsf(mi[q*4+0]-a.x) + fabsf(mi[q*4+1]-a.y) + fabsf(mi[q*4+2]-a.z) + fabsf(mi[q*4+3]-a.w);
        }
        s += __expf(d);
    }
    oT[o] = s;
}

// out[i] = sigmoid( feat[i,:].Wm[0:512] + oT[i,:].Wm[512:576] + bm )
__global__ void final_kernel(const float* __restrict__ feat, const float* __restrict__ oT,
                             const float* __restrict__ Wm, const float* __restrict__ bm,
                             float* __restrict__ out) {
    int i = threadIdx.x;  // 64 threads
    float z = bm[0];
    for (int f = 0; f < 512; f++) z += feat[i * 512 + f] * Wm[f];
    for (int k = 0; k < 64; k++) z += oT[i * 64 + k] * Wm[512 + k];
    out[i] = 1.f / (1.f + __expf(-z));
}

extern "C" void kernel_launch(void* const* d_in, const int* in_sizes, int n_in,
                              void* d_out, int out_size, void* d_ws, size_t ws_size,
                              hipStream_t stream) {
    const float* x  = (const float*)d_in[0];
    const float* w1 = (const float*)d_in[1];
    const float* b1 = (const float*)d_in[2];
    const float* w2 = (const float*)d_in[3];
    const float* b2 = (const float*)d_in[4];
    const float* w3 = (const float*)d_in[5];
    const float* b3 = (const float*)d_in[6];
    const float* w4 = (const float*)d_in[7];
    const float* b4 = (const float*)d_in[8];
    const float* T  = (const float*)d_in[9];
    const float* Wm = (const float*)d_in[10];
    const float* bm = (const float*)d_in[11];

    float* ws   = (float*)d_ws;
    float* w1t  = ws;
    float* w2t  = ws + 3456;
    float* w3t  = ws + 67456;
    float* w4t  = ws + 259456;
    float* h2a  = ws + 342400;
    float* h2b  = ws + 5962112;
    float* h3p  = ws + 11581824;
    float* h3   = ws + 12368256;
    float* feat = ws + 12564864;
    float* Mb   = ws + 12597632;
    float* oT   = ws + 12663168;
    float* h1   = ws + 12667264;

    transpose_w<<<(3456 + 255) / 256, 256, 0, stream>>>(w1, w1t, 16, 216);
    transpose_w<<<(64000 + 255) / 256, 256, 0, stream>>>(w2, w2t, 32, 2000);
    transpose_w<<<(192000 + 255) / 256, 256, 0, stream>>>(w3, w3t, 48, 4000);
    transpose_w<<<(82944 + 255) / 256, 256, 0, stream>>>(w4, w4t, 64, 1296);

    for (int g = 0; g < 4; g++) {
        conv1_kernel<<<1331, 256, 0, stream>>>(x, w1t, b1, h1, g * 16);
        conv2_kernel<<<dim3(172, 2), 256, 0, stream>>>(h1, w2t, h2a, h2b, g);
    }
    combine2<<<21952, 256, 0, stream>>>(h2a, h2b, b2);
    conv3_kernel<<<256, 256, 0, stream>>>(h2a, w3t, h3p);
    combine3<<<768, 256, 0, stream>>>(h3, h3p, b3);
    conv4_kernel<<<128, 256, 0, stream>>>(h3, w4t, b4, feat);
    m_kernel<<<256, 256, 0, stream>>>(feat, T, Mb);
    outt_kernel<<<16, 256, 0, stream>>>(Mb, oT);
    final_kernel<<<1, 64, 0, stream>>>(feat, oT, Wm, bm, (float*)d_out);
}

// Round 2
// 1338.723 us; speedup vs baseline: 1.3593x; 1.3593x over previous
//
#include <hip/hip_runtime.h>
#include <hip/hip_bf16.h>

// ---------------- workspace layout (float offsets) ----------------
// w1t:       0 ..    3456   [tap216][oc16]
// w2t:    3456 ..   67456   [ic*125+tap][oc32]
// w3t:   67456 ..  259456   [ic*125+tap][oc48]
// w4t:  259456 ..  342400   [ic*27+tap][oc64]
// h2a:  342400 .. 5962112   partial conv2 (ic 0..7) -> becomes final h2
// h2b: 5962112 .. 11581824  partial conv2 (ic 8..15)
// h3p: 11581824 .. 14727552 16 partials of conv3 [icg][64,48,64]
// h3:  14727552 .. 14924160
// feat:14924160 .. 14956928 [64][512]
// M:   14956928 .. 15022464 [64][1024]
// oT:  15022464 .. 15026560 [64][64]
// h1:  15026560 .. +NB*16*85184  batch buffer [nb][16oc][44][44][44]

static inline __device__ float leaky(float v) { return v >= 0.f ? v : 0.01f * v; }

__global__ void transpose_all(const float* __restrict__ w1, const float* __restrict__ w2,
                              const float* __restrict__ w3, const float* __restrict__ w4,
                              float* __restrict__ ws) {
    int i = blockIdx.x * 256 + threadIdx.x;
    if (i < 3456) {
        int oc = i & 15, t = i >> 4;
        ws[i] = w1[oc * 216 + t];
    } else if (i < 67456) {
        int j = i - 3456; int oc = j & 31, t = j >> 5;
        ws[i] = w2[oc * 2000 + t];
    } else if (i < 259456) {
        int j = i - 67456; int oc = j % 48, t = j / 48;
        ws[i] = w3[oc * 4000 + t];
    } else if (i < 342400) {
        int j = i - 259456; int oc = j & 63, t = j >> 6;
        ws[i] = w4[oc * 1296 + t];
    }
}

// conv1: x[64,1,92,92,92] -> h1[nb,16,44,44,44], k=6, s=2
// thread: 4 z outputs x 16 oc
__global__ __launch_bounds__(256) void conv1_kernel(
    const float* __restrict__ x, const float* __restrict__ w1t,
    const float* __restrict__ b1, float* __restrict__ h1, int n0, int nthreads) {
    __shared__ float wl[216 * 16];
    int tid = threadIdx.x;
    for (int i = tid; i < 216 * 16; i += 256) wl[i] = w1t[i];
    __syncthreads();

    long o = (long)blockIdx.x * 256 + tid;
    if (o >= nthreads) return;
    int xo = (int)(o % 44); o /= 44;
    int yo = (int)(o % 44); o /= 44;
    int zq = (int)(o % 11);
    int nb = (int)(o / 11);
    int n  = n0 + nb;

    const float* xin = x + (long)n * 778688;  // 92^3
    float acc[4][16];
#pragma unroll
    for (int j = 0; j < 4; j++)
#pragma unroll
        for (int q = 0; q < 16; q++) acc[j][q] = 0.f;

    int z0 = zq * 4;
    int izb = 2 * z0, iyb = 2 * yo, ixb = 2 * xo;

    for (int kz = 0; kz < 6; kz++) {
        for (int ky = 0; ky < 6; ky++) {
            const float* xr = xin + (long)(izb + kz) * 8464 + (iyb + ky) * 92 + ixb;
            float v[4][6];
#pragma unroll
            for (int j = 0; j < 4; j++) {
                const float2* p = (const float2*)(xr + j * 2 * 8464);
                float2 a = p[0], b = p[1], c = p[2];
                v[j][0] = a.x; v[j][1] = a.y; v[j][2] = b.x;
                v[j][3] = b.y; v[j][4] = c.x; v[j][5] = c.y;
            }
            int tbase = (kz * 36 + ky * 6) * 16;
#pragma unroll
            for (int kx = 0; kx < 6; kx++) {
                const float4* wp4 = (const float4*)&wl[tbase + kx * 16];
#pragma unroll
                for (int q = 0; q < 4; q++) {
                    float4 w = wp4[q];
#pragma unroll
                    for (int j = 0; j < 4; j++) {
                        acc[j][q*4+0] += v[j][kx]*w.x; acc[j][q*4+1] += v[j][kx]*w.y;
                        acc[j][q*4+2] += v[j][kx]*w.z; acc[j][q*4+3] += v[j][kx]*w.w;
                    }
                }
            }
        }
    }

#pragma unroll
    for (int oc = 0; oc < 16; oc++) {
        float bb = b1[oc];
#pragma unroll
        for (int j = 0; j < 4; j++) {
            long idx = ((long)(nb * 16 + oc) * 44 + (z0 + j)) * 1936 + yo * 44 + xo;
            h1[idx] = leaky(acc[j][oc] + bb);
        }
    }
}

// conv2: h1[nb,16,44,44,44] -> partials [n,32,14,14,14], k=5, s=3
// thread: 2 z outputs (z, z+7) x 16 oc x 8 ic (icg = blockIdx.y)
__global__ __launch_bounds__(256) void conv2_kernel(
    const float* __restrict__ h1, const float* __restrict__ w2t,
    float* __restrict__ h2a, float* __restrict__ h2b, int n0, int nthreads, int NB) {
    __shared__ float wl[125 * 32];
    int tid = threadIdx.x;
    int icg = blockIdx.y;

    long o = (long)blockIdx.x * 256 + tid;
    bool valid = o < nthreads;
    int xo = 0, yo = 0, zq = 0, nb = 0, ocg = 0;
    if (valid) {
        xo = (int)(o % 14); o /= 14;
        yo = (int)(o % 14); o /= 14;
        zq = (int)(o % 7);  o /= 7;
        nb = (int)(o % NB);
        ocg = (int)(o / NB);
    }

    float acc[2][16];
#pragma unroll
    for (int j = 0; j < 2; j++)
#pragma unroll
        for (int q = 0; q < 16; q++) acc[j][q] = 0.f;

    const float* xin = h1 + (long)nb * 16 * 85184;

    for (int ic = 0; ic < 8; ic++) {
        int ica = icg * 8 + ic;
        __syncthreads();
        for (int i = tid; i < 4000; i += 256) wl[i] = w2t[(long)ica * 4000 + i];
        __syncthreads();
        if (!valid) continue;
        const float* xc = xin + (long)ica * 85184;
        for (int kz = 0; kz < 5; kz++) {
            int iz = 3 * zq + kz;
            for (int ky = 0; ky < 5; ky++) {
                const float* xr = xc + (iz * 44 + (3 * yo + ky)) * 44 + 3 * xo;
                int tb = ((kz * 5 + ky) * 5) * 32 + ocg * 16;
#pragma unroll
                for (int kx = 0; kx < 5; kx++) {
                    float v0 = xr[kx];
                    float v1 = xr[kx + 21 * 1936];  // z+7 -> iz+21
                    const float4* wp = (const float4*)&wl[tb + kx * 32];
#pragma unroll
                    for (int q = 0; q < 4; q++) {
                        float4 w = wp[q];
                        acc[0][q*4+0] += v0*w.x; acc[0][q*4+1] += v0*w.y; acc[0][q*4+2] += v0*w.z; acc[0][q*4+3] += v0*w.w;
                        acc[1][q*4+0] += v1*w.x; acc[1][q*4+1] += v1*w.y; acc[1][q*4+2] += v1*w.z; acc[1][q*4+3] += v1*w.w;
                    }
                }
            }
        }
    }

    if (valid) {
        float* dst = (icg == 0) ? h2a : h2b;
        int n = n0 + nb;
#pragma unroll
        for (int j = 0; j < 2; j++) {
            int z = zq + j * 7;
            long base = ((long)(n * 32 + ocg * 16)) * 2744 + (z * 14 + yo) * 14 + xo;
#pragma unroll
            for (int q = 0; q < 16; q++) dst[base + (long)q * 2744] = acc[j][q];
        }
    }
}

// h2 = leaky(h2a + h2b + b2[oc]) in-place into h2a
__global__ void combine2(float* __restrict__ a, const float* __restrict__ b,
                         const float* __restrict__ b2) {
    long i = (long)blockIdx.x * 256 + threadIdx.x;  // 5619712 = 21952*256
    int oc = (int)((i / 2744) % 32);
    a[i] = leaky(a[i] + b[i] + b2[oc]);
}

// conv3: h2[64,32,14,14,14] -> h3p[icg][64,48,4,4,4], k=5, s=3
// block = (n, icg of 2 ic); wave = 12 oc; lane = 64 positions; weights in LDS
__global__ __launch_bounds__(256) void conv3_kernel(
    const float* __restrict__ h2, const float* __restrict__ w3t,
    float* __restrict__ h3p) {
    __shared__ float wl[12000];  // 2 ic x 125 taps x 48 oc
    int n   = blockIdx.x;
    int icg = blockIdx.y;
    int tid = threadIdx.x;
    for (int i = tid; i < 12000; i += 256) wl[i] = w3t[(long)icg * 12000 + i];
    __syncthreads();

    int lane = tid & 63, wv = tid >> 6;
    int ocb  = wv * 12;
    int xo = lane & 3, yo = (lane >> 2) & 3, zo = lane >> 4;

    float acc[12];
#pragma unroll
    for (int q = 0; q < 12; q++) acc[q] = 0.f;

#pragma unroll
    for (int ic2 = 0; ic2 < 2; ic2++) {
        const float* xc = h2 + ((long)n * 32 + icg * 2 + ic2) * 2744;
        for (int kz = 0; kz < 5; kz++) {
            for (int ky = 0; ky < 5; ky++) {
                const float* xr = xc + ((3 * zo + kz) * 14 + 3 * yo + ky) * 14 + 3 * xo;
                int tb = (ic2 * 125 + (kz * 5 + ky) * 5) * 48 + ocb;
#pragma unroll
                for (int kx = 0; kx < 5; kx++) {
                    float v = xr[kx];
                    const float4* wp = (const float4*)&wl[tb + kx * 48];
#pragma unroll
                    for (int q = 0; q < 3; q++) {
                        float4 w = wp[q];
                        acc[q*4+0] += v*w.x; acc[q*4+1] += v*w.y; acc[q*4+2] += v*w.z; acc[q*4+3] += v*w.w;
                    }
                }
            }
        }
    }
    float* outp = h3p + (long)icg * 196608 + ((long)n * 48 + ocb) * 64 + lane;
#pragma unroll
    for (int j = 0; j < 12; j++) outp[(long)j * 64] = acc[j];
}

// h3 = leaky(sum of 16 partials + b3[oc])
__global__ void combine3(float* __restrict__ h3, const float* __restrict__ h3p,
                         const float* __restrict__ b3) {
    long i = (long)blockIdx.x * 256 + threadIdx.x;  // 196608 = 768*256
    int oc = (int)((i / 64) % 48);
    float v = b3[oc];
#pragma unroll
    for (int p = 0; p < 16; p++) v += h3p[i + (long)p * 196608];
    h3[i] = leaky(v);
}

// conv4: h3[64,48,4,4,4] -> feat[64,512], k=3, s=1
__global__ void conv4_kernel(const float* __restrict__ h3, const float* __restrict__ w4t,
                             const float* __restrict__ b4, float* __restrict__ feat) {
    int o = blockIdx.x * 256 + threadIdx.x;  // 32768 = 128*256
    int pos = o & 7;
    int oc  = (o >> 3) & 63;
    int n   = o >> 9;
    int px = pos & 1, py = (pos >> 1) & 1, pz = pos >> 2;
    const float* xn = h3 + (long)n * 48 * 64;
    float acc = 0.f;
    for (int ic = 0; ic < 48; ic++) {
        const float* xc = xn + ic * 64;
        int tb = ic * 27;
#pragma unroll
        for (int kz = 0; kz < 3; kz++)
#pragma unroll
            for (int ky = 0; ky < 3; ky++)
#pragma unroll
                for (int kx = 0; kx < 3; kx++) {
                    float v = xc[(pz + kz) * 16 + (py + ky) * 4 + (px + kx)];
                    acc += v * w4t[(long)(tb + (kz * 3 + ky) * 3 + kx) * 64 + oc];
                }
    }
    feat[o] = leaky(acc + b4[oc]);  // o == n*512 + oc*8 + pos
}

// M[64,1024] = feat[64,512] @ T[512,1024]
__global__ void m_kernel(const float* __restrict__ feat, const float* __restrict__ T,
                         float* __restrict__ M) {
    int o = blockIdx.x * 256 + threadIdx.x;  // 65536 = 256*256
    int col = o & 1023;
    int n   = o >> 10;
    const float* fr = feat + n * 512;
    float acc = 0.f;
#pragma unroll 4
    for (int f = 0; f < 512; f++) acc += fr[f] * T[f * 1024 + col];
    M[o] = acc;
}

// out_T[i,k] = sum_j exp( sum_l |M[i,k,l]-M[j,k,l]| )
__global__ void outt_kernel(const float* __restrict__ M, float* __restrict__ oT) {
    int o = blockIdx.x * 256 + threadIdx.x;  // 4096 = 16*256
    int k = o & 63;
    int i = o >> 6;
    float mi[16];
    const float4* Mi = (const float4*)(M + i * 1024 + k * 16);
#pragma unroll
    for (int q = 0; q < 4; q++) {
        float4 a = Mi[q];
        mi[q*4+0] = a.x; mi[q*4+1] = a.y; mi[q*4+2] = a.z; mi[q*4+3] = a.w;
    }
    float s = 0.f;
    for (int j = 0; j < 64; j++) {
        const float4* Mj = (const float4*)(M + j * 1024 + k * 16);
        float d = 0.f;
#pragma unroll
        for (int q = 0; q < 4; q++) {
            float4 a = Mj[q];
            d += fabsf(mi[q*4+0]-a.x) + fabsf(mi[q*4+1]-a.y) + fabsf(mi[q*4+2]-a.z) + fabsf(mi[q*4+3]-a.w);
        }
        s += __expf(d);
    }
    oT[o] = s;
}

// out[i] = sigmoid( feat[i,:].Wm[0:512] + oT[i,:].Wm[512:576] + bm )
__global__ void final_kernel(const float* __restrict__ feat, const float* __restrict__ oT,
                             const float* __restrict__ Wm, const float* __restrict__ bm,
                             float* __restrict__ out) {
    int i = blockIdx.x;      // 64 outputs
    int lane = threadIdx.x;  // 64 lanes
    const float* fr = feat + i * 512;
    float z = 0.f;
#pragma unroll
    for (int q = 0; q < 8; q++) z += fr[lane + q * 64] * Wm[lane + q * 64];
    z += oT[i * 64 + lane] * Wm[512 + lane];
#pragma unroll
    for (int off = 32; off > 0; off >>= 1) z += __shfl_down(z, off);
    if (lane == 0) out[i] = 1.f / (1.f + __expf(-(z + bm[0])));
}

extern "C" void kernel_launch(void* const* d_in, const int* in_sizes, int n_in,
                              void* d_out, int out_size, void* d_ws, size_t ws_size,
                              hipStream_t stream) {
    const float* x  = (const float*)d_in[0];
    const float* w1 = (const float*)d_in[1];
    const float* b1 = (const float*)d_in[2];
    const float* w2 = (const float*)d_in[3];
    const float* b2 = (const float*)d_in[4];
    const float* w3 = (const float*)d_in[5];
    const float* b3 = (const float*)d_in[6];
    const float* w4 = (const float*)d_in[7];
    const float* b4 = (const float*)d_in[8];
    const float* T  = (const float*)d_in[9];
    const float* Wm = (const float*)d_in[10];
    const float* bm = (const float*)d_in[11];

    float* ws   = (float*)d_ws;
    float* w1t  = ws;
    float* w2t  = ws + 3456;
    float* w3t  = ws + 67456;
    float* w4t  = ws + 259456;
    float* h2a  = ws + 342400;
    float* h2b  = ws + 5962112;
    float* h3p  = ws + 11581824;
    float* h3   = ws + 14727552;
    float* feat = ws + 14924160;
    float* Mb   = ws + 14956928;
    float* oT   = ws + 15022464;
    float* h1   = ws + 15026560;

    transpose_all<<<(342400 + 255) / 256, 256, 0, stream>>>(w1, w2, w3, w4, ws);

    // pick batch-group size by available workspace
    int NB;
    if (ws_size >= (size_t)(15026560 + 64ll * 16 * 85184) * 4) NB = 64;
    else if (ws_size >= (size_t)(15026560 + 16ll * 16 * 85184) * 4) NB = 16;
    else NB = 8;

    for (int n0 = 0; n0 < 64; n0 += NB) {
        int nt1 = NB * 21296;  // NB * 11 * 44 * 44
        conv1_kernel<<<(nt1 + 255) / 256, 256, 0, stream>>>(x, w1t, b1, h1, n0, nt1);
        int nt2 = NB * 2744;   // NB * 7 * 14 * 14 * 2
        conv2_kernel<<<dim3((nt2 + 255) / 256, 2), 256, 0, stream>>>(h1, w2t, h2a, h2b, n0, nt2, NB);
    }
    combine2<<<21952, 256, 0, stream>>>(h2a, h2b, b2);
    conv3_kernel<<<dim3(64, 16), 256, 0, stream>>>(h2a, w3t, h3p);
    combine3<<<768, 256, 0, stream>>>(h3, h3p, b3);
    conv4_kernel<<<128, 256, 0, stream>>>(h3, w4t, b4, feat);
    m_kernel<<<256, 256, 0, stream>>>(feat, T, Mb);
    outt_kernel<<<16, 256, 0, stream>>>(Mb, oT);
    final_kernel<<<64, 64, 0, stream>>>(feat, oT, Wm, bm, (float*)d_out);
}

// Round 4
// 876.393 us; speedup vs baseline: 2.0764x; 1.5275x over previous
//
#include <hip/hip_runtime.h>
#include <hip/hip_bf16.h>
#include <hip/hip_fp16.h>

typedef _Float16 v2h __attribute__((ext_vector_type(2)));
typedef _Float16 v8h __attribute__((ext_vector_type(8)));
typedef __fp16  v2hf __attribute__((ext_vector_type(2)));
typedef float v4f __attribute__((ext_vector_type(4)));

static inline __device__ float leaky(float v) { return v >= 0.f ? v : 0.01f * v; }

static inline __device__ v2h pkrtz(float a, float b) {
    v2hf r = __builtin_amdgcn_cvt_pkrtz(a, b);
    return __builtin_bit_cast(v2h, r);
}

#if __has_builtin(__builtin_amdgcn_fdot2)
static inline __device__ float fdot2(v2h a, v2h b, float c) {
    return __builtin_amdgcn_fdot2(a, b, c, false);
}
#else
static inline __device__ float fdot2(v2h a, v2h b, float c) {
    return c + (float)a[0] * (float)b[0] + (float)a[1] * (float)b[1];
}
#endif

// ---------------- workspace layout ----------------
// f32 region (element offsets from ws):
#define W4T_OFF   0          // 82944
#define H3P_OFF   82944      // 8 * 196608 = 1572864
#define H3_OFF    1655808    // 196608
#define FEAT_OFF  1852416    // 32768
#define M_OFF     1885184    // 65536
#define OT_OFF    1950720    // 4096
// f16 region starts at f32 offset 1954816 (byte 7819264):
#define F16_BASE  1954816
#define WL1_OFF   0          // 3456   conv1 weights [kz6][ky6][kxp3][oc16][2]
#define BF2_OFF   3456       // 76800  conv2 B-frags [nt2][kstep75][lane64][8]
#define BF3_OFF   80256      // 192000 conv3 B-frags [nt3][tap125][lane64][8]
#define H2C_OFF   272256     // 5619712 h2 channels-last [m175616][oc32]
#define H1C_OFF   5891968    // NB*1362944 + pad

// ---------------- weight prep ----------------
__global__ void prep_kernel(const float* __restrict__ w1, const float* __restrict__ w2,
                            const float* __restrict__ w3, const float* __restrict__ w4,
                            float* __restrict__ w4t, _Float16* __restrict__ wl1,
                            _Float16* __restrict__ Bf2, _Float16* __restrict__ Bf3) {
    int i = blockIdx.x * 256 + threadIdx.x;
    if (i < 3456) {
        int s = i & 1, oc = (i >> 1) & 15, kk = i >> 5;
        int kxp = kk % 3, ky = (kk / 3) % 6, kz = kk / 18;
        wl1[i] = (_Float16)w1[oc * 216 + kz * 36 + ky * 6 + kxp * 2 + s];
    } else if (i < 3456 + 76800) {
        int j2 = i - 3456;
        int nt = j2 / 38400, r = j2 % 38400;
        int t = r / 512, l = (r % 512) >> 3, j = r & 7;
        int oc = nt * 16 + (l & 15);
        int k = (l >> 4) * 8 + j;
        int kz = t / 15, ky = (t % 15) / 3, kxp = t % 3;
        int kx = kxp * 2 + (k >= 16 ? 1 : 0);
        int ic = k & 15;
        Bf2[j2] = (kx < 5) ? (_Float16)w2[oc * 2000 + ic * 125 + kz * 25 + ky * 5 + kx]
                           : (_Float16)0.f;
    } else if (i < 3456 + 76800 + 192000) {
        int j3 = i - (3456 + 76800);
        int nt = j3 / 64000, r = j3 % 64000;
        int tap = r / 512, l = (r % 512) >> 3, j = r & 7;
        int oc = nt * 16 + (l & 15);
        int ic = (l >> 4) * 8 + j;
        Bf3[j3] = (_Float16)w3[oc * 4000 + ic * 125 + tap];
    } else {
        int j4 = i - (3456 + 76800 + 192000);
        if (j4 < 82944) {
            int oc = j4 & 63, t = j4 >> 6;
            w4t[j4] = w4[oc * 1296 + t];
        }
    }
}

// ---------------- conv1: f16 dot2, writes h1 channels-last f16 ----------------
// x[64,92^3] f32 -> h1c[nb][z44][y44][x44][oc16] f16, k=6, s=2
// thread: 4 z x 16 oc
__global__ __launch_bounds__(256) void conv1_kernel(
    const float* __restrict__ x, const _Float16* __restrict__ wl1g,
    const float* __restrict__ b1, _Float16* __restrict__ h1c, int n0, int nth) {
    __shared__ __align__(16) _Float16 wl[3456];
    int tid = threadIdx.x;
    {
        const v8h* src = (const v8h*)wl1g;
        v8h* dst = (v8h*)wl;
        for (int i2 = tid; i2 < 432; i2 += 256) dst[i2] = src[i2];
    }
    __syncthreads();

    long o = (long)blockIdx.x * 256 + tid;
    if (o >= nth) return;
    int xo = (int)(o % 44); o /= 44;
    int yo = (int)(o % 44); o /= 44;
    int zq = (int)(o % 11);
    int nb = (int)(o / 11);

    const float* xin = x + (long)(n0 + nb) * 778688;
    float acc[4][16];
#pragma unroll
    for (int j = 0; j < 4; j++)
#pragma unroll
        for (int q = 0; q < 16; q++) acc[j][q] = 0.f;

    int z0 = zq * 4;
    int izb = 2 * z0, iyb = 2 * yo, ixb = 2 * xo;

    for (int kz = 0; kz < 6; kz++) {
        for (int ky = 0; ky < 6; ky++) {
            const float* xr = xin + (long)(izb + kz) * 8464 + (iyb + ky) * 92 + ixb;
            v2h v[4][3];
#pragma unroll
            for (int j = 0; j < 4; j++) {
                const float2* p = (const float2*)(xr + j * 2 * 8464);
                float2 a = p[0], b = p[1], c = p[2];
                v[j][0] = pkrtz(a.x, a.y);
                v[j][1] = pkrtz(b.x, b.y);
                v[j][2] = pkrtz(c.x, c.y);
            }
            const _Float16* wb = wl + (kz * 6 + ky) * 96;
#pragma unroll
            for (int kxp = 0; kxp < 3; kxp++) {
#pragma unroll
                for (int q = 0; q < 4; q++) {
                    v8h wv = *(const v8h*)(wb + kxp * 32 + q * 8);
                    v2h w0 = {wv[0], wv[1]}, w1_ = {wv[2], wv[3]};
                    v2h w2_ = {wv[4], wv[5]}, w3_ = {wv[6], wv[7]};
#pragma unroll
                    for (int j = 0; j < 4; j++) {
                        acc[j][q*4+0] = fdot2(v[j][kxp], w0,  acc[j][q*4+0]);
                        acc[j][q*4+1] = fdot2(v[j][kxp], w1_, acc[j][q*4+1]);
                        acc[j][q*4+2] = fdot2(v[j][kxp], w2_, acc[j][q*4+2]);
                        acc[j][q*4+3] = fdot2(v[j][kxp], w3_, acc[j][q*4+3]);
                    }
                }
            }
        }
    }

#pragma unroll
    for (int j = 0; j < 4; j++) {
        union { v2h h2[8]; uint4 u4[2]; } u;
#pragma unroll
        for (int p = 0; p < 8; p++) {
            float e0 = leaky(acc[j][2*p]   + b1[2*p]);
            float e1 = leaky(acc[j][2*p+1] + b1[2*p+1]);
            u.h2[p] = pkrtz(e0, e1);
        }
        _Float16* dst = h1c + ((long)((nb * 44 + z0 + j) * 44 + yo) * 44 + xo) * 16;
        *(uint4*)dst = u.u4[0];
        *((uint4*)dst + 1) = u.u4[1];
    }
}

// ---------------- conv2: MFMA implicit GEMM ----------------
// h1c[nb][iz][iy][ix][ic16] f16 -> h2c[m][oc32] f16, k=5, s=3
// wave: 2 M-tiles (16 pos each) x 32 oc; K = 150 padded taps x 16 ic, 75 ksteps
__global__ __launch_bounds__(256) void conv2_kernel(
    const _Float16* __restrict__ h1c, const _Float16* __restrict__ Bf2,
    const float* __restrict__ b2, _Float16* __restrict__ h2c, int n0, int mlimit) {
    int tid = threadIdx.x;
    int lane = tid & 63, wv = tid >> 6;
    int t0 = (blockIdx.x * 4 + wv) * 2;
    int col = lane & 15, kgrp = lane >> 4;
    int par = kgrp >> 1, ico = (kgrp & 1) * 8;

    int base[2];
    bool valid[2];
#pragma unroll
    for (int i = 0; i < 2; i++) {
        int m = (t0 + i) * 16 + col;
        valid[i] = m < mlimit;
        int mm = valid[i] ? m : 0;
        int nl = mm / 2744, r = mm % 2744;
        int z = r / 196; r %= 196;
        int y = r / 14, xx = r % 14;
        base[i] = nl * 1362944 + z * 3 * 30976 + y * 3 * 704 + xx * 3 * 16 + ico + par * 16;
    }

    v4f acc[2][2];
#pragma unroll
    for (int i = 0; i < 2; i++)
#pragma unroll
        for (int nt = 0; nt < 2; nt++) acc[i][nt] = (v4f){0.f, 0.f, 0.f, 0.f};

    int t = 0;
    for (int kz = 0; kz < 5; kz++) {
        for (int ky = 0; ky < 5; ky++) {
#pragma unroll
            for (int kxp = 0; kxp < 3; kxp++, t++) {
                int d = kz * 30976 + ky * 704 + kxp * 32;
                v8h A0 = *(const v8h*)(h1c + base[0] + d);
                v8h A1 = *(const v8h*)(h1c + base[1] + d);
                v8h B0 = *(const v8h*)(Bf2 + t * 512 + lane * 8);
                v8h B1 = *(const v8h*)(Bf2 + (75 + t) * 512 + lane * 8);
                acc[0][0] = __builtin_amdgcn_mfma_f32_16x16x32_f16(A0, B0, acc[0][0], 0, 0, 0);
                acc[0][1] = __builtin_amdgcn_mfma_f32_16x16x32_f16(A0, B1, acc[0][1], 0, 0, 0);
                acc[1][0] = __builtin_amdgcn_mfma_f32_16x16x32_f16(A1, B0, acc[1][0], 0, 0, 0);
                acc[1][1] = __builtin_amdgcn_mfma_f32_16x16x32_f16(A1, B1, acc[1][1], 0, 0, 0);
            }
        }
    }

#pragma unroll
    for (int i = 0; i < 2; i++) {
        if (!valid[i]) continue;
#pragma unroll
        for (int nt = 0; nt < 2; nt++) {
            int oc = nt * 16 + col;
            float bb = b2[oc];
#pragma unroll
            for (int reg = 0; reg < 4; reg++) {
                int mlocal = (t0 + i) * 16 + kgrp * 4 + reg;
                float vv = leaky(acc[i][nt][reg] + bb);
                h2c[(long)(n0 * 2744 + mlocal) * 32 + oc] = (_Float16)vv;
            }
        }
    }
}

// ---------------- conv3: MFMA implicit GEMM, K-split x8 ----------------
// h2c[m2744n][ic32] f16 -> h3p[chunk8][m4096][oc48] f32 partials, k=5, s=3
__global__ __launch_bounds__(256) void conv3_kernel(
    const _Float16* __restrict__ h2c, const _Float16* __restrict__ Bf3,
    float* __restrict__ h3p) {
    int tid = threadIdx.x;
    int lane = tid & 63, wv = tid >> 6;
    int mt = blockIdx.x * 4 + wv;   // 0..255
    int chunk = blockIdx.y;         // 0..7
    int col = lane & 15, kgrp = lane >> 4;
    int m = mt * 16 + col;
    int n = m >> 6, pos = m & 63;
    int z = pos >> 4, y = (pos >> 2) & 3, xx = pos & 3;
    int base = (n * 2744 + z * 3 * 196 + y * 3 * 14 + xx * 3) * 32 + kgrp * 8;

    v4f acc[3];
#pragma unroll
    for (int nt = 0; nt < 3; nt++) acc[nt] = (v4f){0.f, 0.f, 0.f, 0.f};

    int tap0 = chunk * 16;
    int tap1 = tap0 + 16 < 125 ? tap0 + 16 : 125;
    for (int tap = tap0; tap < tap1; tap++) {
        int kz = tap / 25, rr = tap % 25, ky = rr / 5, kx = rr % 5;
        int d = (kz * 196 + ky * 14 + kx) * 32;
        v8h A  = *(const v8h*)(h2c + base + d);
        v8h B0 = *(const v8h*)(Bf3 + tap * 512 + lane * 8);
        v8h B1 = *(const v8h*)(Bf3 + (125 + tap) * 512 + lane * 8);
        v8h B2 = *(const v8h*)(Bf3 + (250 + tap) * 512 + lane * 8);
        acc[0] = __builtin_amdgcn_mfma_f32_16x16x32_f16(A, B0, acc[0], 0, 0, 0);
        acc[1] = __builtin_amdgcn_mfma_f32_16x16x32_f16(A, B1, acc[1], 0, 0, 0);
        acc[2] = __builtin_amdgcn_mfma_f32_16x16x32_f16(A, B2, acc[2], 0, 0, 0);
    }

    float* outp = h3p + (long)chunk * 196608;
#pragma unroll
    for (int nt = 0; nt < 3; nt++)
#pragma unroll
        for (int reg = 0; reg < 4; reg++) {
            int md = mt * 16 + kgrp * 4 + reg;
            outp[md * 48 + nt * 16 + col] = acc[nt][reg];
        }
}

// h3[n][oc48][pos64] = leaky(sum of 8 partials + b3)
__global__ void combine3(float* __restrict__ h3, const float* __restrict__ h3p,
                         const float* __restrict__ b3) {
    int i = blockIdx.x * 256 + threadIdx.x;  // 196608 = 768*256
    int m = i / 48, oc = i % 48;
    float v = b3[oc];
#pragma unroll
    for (int p = 0; p < 8; p++) v += h3p[i + p * 196608];
    h3[((m >> 6) * 48 + oc) * 64 + (m & 63)] = leaky(v);
}

// conv4: h3[64,48,4,4,4] f32 -> feat[64,512], k=3, s=1
__global__ void conv4_kernel(const float* __restrict__ h3, const float* __restrict__ w4t,
                             const float* __restrict__ b4, float* __restrict__ feat) {
    int o = blockIdx.x * 256 + threadIdx.x;  // 32768 = 128*256
    int pos = o & 7;
    int oc  = (o >> 3) & 63;
    int n   = o >> 9;
    int px = pos & 1, py = (pos >> 1) & 1, pz = pos >> 2;
    const float* xn = h3 + (long)n * 48 * 64;
    float acc = 0.f;
    for (int ic = 0; ic < 48; ic++) {
        const float* xc = xn + ic * 64;
        int tb = ic * 27;
#pragma unroll
        for (int kz = 0; kz < 3; kz++)
#pragma unroll
            for (int ky = 0; ky < 3; ky++)
#pragma unroll
                for (int kx = 0; kx < 3; kx++) {
                    float v = xc[(pz + kz) * 16 + (py + ky) * 4 + (px + kx)];
                    acc += v * w4t[(tb + (kz * 3 + ky) * 3 + kx) * 64 + oc];
                }
    }
    feat[o] = leaky(acc + b4[oc]);  // o == n*512 + oc*8 + pos
}

// M[64,1024] = feat[64,512] @ T[512,1024]
__global__ void m_kernel(const float* __restrict__ feat, const float* __restrict__ T,
                         float* __restrict__ M) {
    int o = blockIdx.x * 256 + threadIdx.x;  // 65536 = 256*256
    int col = o & 1023;
    int n   = o >> 10;
    const float* fr = feat + n * 512;
    float acc = 0.f;
#pragma unroll 4
    for (int f = 0; f < 512; f++) acc += fr[f] * T[f * 1024 + col];
    M[o] = acc;
}

// out_T[i,k] = sum_j exp( sum_l |M[i,k,l]-M[j,k,l]| )
__global__ void outt_kernel(const float* __restrict__ M, float* __restrict__ oT) {
    int o = blockIdx.x * 256 + threadIdx.x;  // 4096 = 16*256
    int k = o & 63;
    int i = o >> 6;
    float mi[16];
    const float4* Mi = (const float4*)(M + i * 1024 + k * 16);
#pragma unroll
    for (int q = 0; q < 4; q++) {
        float4 a = Mi[q];
        mi[q*4+0] = a.x; mi[q*4+1] = a.y; mi[q*4+2] = a.z; mi[q*4+3] = a.w;
    }
    float s = 0.f;
    for (int j = 0; j < 64; j++) {
        const float4* Mj = (const float4*)(M + j * 1024 + k * 16);
        float d = 0.f;
#pragma unroll
        for (int q = 0; q < 4; q++) {
            float4 a = Mj[q];
            d += fabsf(mi[q*4+0]-a.x) + fabsf(mi[q*4+1]-a.y) + fabsf(mi[q*4+2]-a.z) + fabsf(mi[q*4+3]-a.w);
        }
        s += __expf(d);
    }
    oT[o] = s;
}

// out[i] = sigmoid( feat[i,:].Wm[0:512] + oT[i,:].Wm[512:576] + bm )
__global__ void final_kernel(const float* __restrict__ feat, const float* __restrict__ oT,
                             const float* __restrict__ Wm, const float* __restrict__ bm,
                             float* __restrict__ out) {
    int i = blockIdx.x;      // 64 outputs
    int lane = threadIdx.x;  // 64 lanes
    const float* fr = feat + i * 512;
    float z = 0.f;
#pragma unroll
    for (int q = 0; q < 8; q++) z += fr[lane + q * 64] * Wm[lane + q * 64];
    z += oT[i * 64 + lane] * Wm[512 + lane];
#pragma unroll
    for (int off = 32; off > 0; off >>= 1) z += __shfl_down(z, off);
    if (lane == 0) out[i] = 1.f / (1.f + __expf(-(z + bm[0])));
}

extern "C" void kernel_launch(void* const* d_in, const int* in_sizes, int n_in,
                              void* d_out, int out_size, void* d_ws, size_t ws_size,
                              hipStream_t stream) {
    const float* x  = (const float*)d_in[0];
    const float* w1 = (const float*)d_in[1];
    const float* b1 = (const float*)d_in[2];
    const float* w2 = (const float*)d_in[3];
    const float* b2 = (const float*)d_in[4];
    const float* w3 = (const float*)d_in[5];
    const float* b3 = (const float*)d_in[6];
    const float* w4 = (const float*)d_in[7];
    const float* b4 = (const float*)d_in[8];
    const float* T  = (const float*)d_in[9];
    const float* Wm = (const float*)d_in[10];
    const float* bm = (const float*)d_in[11];

    float* ws   = (float*)d_ws;
    float* w4t  = ws + W4T_OFF;
    float* h3p  = ws + H3P_OFF;
    float* h3   = ws + H3_OFF;
    float* feat = ws + FEAT_OFF;
    float* Mb   = ws + M_OFF;
    float* oT   = ws + OT_OFF;
    _Float16* f16b = (_Float16*)(ws + F16_BASE);
    _Float16* wl1  = f16b + WL1_OFF;
    _Float16* Bf2  = f16b + BF2_OFF;
    _Float16* Bf3  = f16b + BF3_OFF;
    _Float16* h2c  = f16b + H2C_OFF;
    _Float16* h1c  = f16b + H1C_OFF;

    prep_kernel<<<1388, 256, 0, stream>>>(w1, w2, w3, w4, w4t, wl1, Bf2, Bf3);

    // choose batch-group size by workspace capacity
    size_t fixed_bytes = (size_t)F16_BASE * 4 + (size_t)H1C_OFF * 2;
    int NB;
    if (ws_size >= fixed_bytes + (64ll * 1362944 + 64) * 2) NB = 64;
    else if (ws_size >= fixed_bytes + (16ll * 1362944 + 64) * 2) NB = 16;
    else NB = 8;

    for (int n0 = 0; n0 < 64; n0 += NB) {
        int nth = NB * 21296;
        conv1_kernel<<<(nth + 255) / 256, 256, 0, stream>>>(x, wl1, b1, h1c, n0, nth);
        int mlimit = NB * 2744;
        int blocks2 = (mlimit + 127) / 128;  // 2 tiles x 16 pos x 4 waves
        conv2_kernel<<<blocks2, 256, 0, stream>>>(h1c, Bf2, b2, h2c, n0, mlimit);
    }
    conv3_kernel<<<dim3(64, 8), 256, 0, stream>>>(h2c, Bf3, h3p);
    combine3<<<768, 256, 0, stream>>>(h3, h3p, b3);
    conv4_kernel<<<128, 256, 0, stream>>>(h3, w4t, b4, feat);
    m_kernel<<<256, 256, 0, stream>>>(feat, T, Mb);
    outt_kernel<<<16, 256, 0, stream>>>(Mb, oT);
    final_kernel<<<64, 64, 0, stream>>>(feat, oT, Wm, bm, (float*)d_out);
}